// Round 1
// baseline (11402.972 us; speedup 1.0000x reference)
//
#include <hip/hip_runtime.h>
#include <math.h>

#define D_MODEL 768
#define D_INNER 1536
#define D_STATE 16
#define DT_RANK 48
#define NLAYERS 24
#define BATCH 2
#define SEQ 256
#define M_ROWS (BATCH*SEQ)   // 512
#define DBC_COLS (DT_RANK + 2*D_STATE)  // 80

__device__ __forceinline__ float siluf(float x) {
    return x / (1.0f + expf(-x));
}

// ---------------- embedding gather: h[m,:] = embed[ids[m],:] ----------------
__global__ __launch_bounds__(256) void gather_kernel(const int* __restrict__ ids,
        const float* __restrict__ embed, float* __restrict__ h) {
    int m = blockIdx.x;
    long id = ids[m];
    const float* src = embed + id * D_MODEL;
    float* dst = h + m * D_MODEL;
    for (int k = threadIdx.x; k < D_MODEL; k += 256) dst[k] = src[k];
}

// ---------------- RMS norm: x[m,:] = h[m,:] * rsqrt(mean(h^2)+eps) * w ------
__global__ __launch_bounds__(256) void rmsnorm_kernel(const float* __restrict__ h,
        const float* __restrict__ w, float* __restrict__ x) {
    int m = blockIdx.x;
    const float* row = h + m * D_MODEL;
    float v[3];
    float ss = 0.f;
    #pragma unroll
    for (int i = 0; i < 3; ++i) {
        v[i] = row[threadIdx.x + i * 256];
        ss += v[i] * v[i];
    }
    #pragma unroll
    for (int off = 32; off > 0; off >>= 1) ss += __shfl_down(ss, off);
    __shared__ float wsum[4];
    int lane = threadIdx.x & 63, wid = threadIdx.x >> 6;
    if (lane == 0) wsum[wid] = ss;
    __syncthreads();
    float tot = wsum[0] + wsum[1] + wsum[2] + wsum[3];
    float inv = rsqrtf(tot / (float)D_MODEL + 1e-5f);
    float* xrow = x + m * D_MODEL;
    #pragma unroll
    for (int i = 0; i < 3; ++i) {
        int k = threadIdx.x + i * 256;
        xrow[k] = v[i] * inv * w[k];
    }
}

// ---------------- NT GEMM: C[M,N] (op)= A[M,K(lda)] * B[N,K]^T --------------
// epi: 0 = store, 1 = softplus(acc + bias[n]) store, 2 = accumulate (+=)
#define KT 16
__global__ __launch_bounds__(256) void gemm_nt(const float* __restrict__ A,
        const float* __restrict__ B, float* __restrict__ C,
        int M, int N, int K, int lda,
        const float* __restrict__ bias, int epi) {
    __shared__ __align__(16) float As[KT][68];
    __shared__ __align__(16) float Bs[KT][68];
    int tx = threadIdx.x;           // 0..15 -> n
    int ty = threadIdx.y;           // 0..15 -> m
    int tid = ty * 16 + tx;
    int m0 = blockIdx.y * 64, n0 = blockIdx.x * 64;
    int lr = tid >> 2;              // 0..63 tile row
    int lc = (tid & 3) * 4;         // 0,4,8,12 k offset
    const float* Aptr = A + (long)(m0 + lr) * lda + lc;
    const float* Bptr = B + (long)(n0 + lr) * K + lc;
    bool bvalid = (n0 + lr) < N;
    float acc[4][4] = {};
    for (int k0 = 0; k0 < K; k0 += KT) {
        float4 av = *(const float4*)(Aptr + k0);
        float4 bv = bvalid ? *(const float4*)(Bptr + k0) : make_float4(0.f, 0.f, 0.f, 0.f);
        As[lc + 0][lr] = av.x; As[lc + 1][lr] = av.y;
        As[lc + 2][lr] = av.z; As[lc + 3][lr] = av.w;
        Bs[lc + 0][lr] = bv.x; Bs[lc + 1][lr] = bv.y;
        Bs[lc + 2][lr] = bv.z; Bs[lc + 3][lr] = bv.w;
        __syncthreads();
        #pragma unroll
        for (int kk = 0; kk < KT; ++kk) {
            float4 a = *(const float4*)&As[kk][ty * 4];
            float4 b = *(const float4*)&Bs[kk][tx * 4];
            acc[0][0] += a.x * b.x; acc[0][1] += a.x * b.y; acc[0][2] += a.x * b.z; acc[0][3] += a.x * b.w;
            acc[1][0] += a.y * b.x; acc[1][1] += a.y * b.y; acc[1][2] += a.y * b.z; acc[1][3] += a.y * b.w;
            acc[2][0] += a.z * b.x; acc[2][1] += a.z * b.y; acc[2][2] += a.z * b.z; acc[2][3] += a.z * b.w;
            acc[3][0] += a.w * b.x; acc[3][1] += a.w * b.y; acc[3][2] += a.w * b.z; acc[3][3] += a.w * b.w;
        }
        __syncthreads();
    }
    int m = m0 + ty * 4, n = n0 + tx * 4;
    #pragma unroll
    for (int i = 0; i < 4; ++i) {
        #pragma unroll
        for (int j = 0; j < 4; ++j) {
            int nn = n + j;
            if (nn < N) {
                float vv = acc[i][j];
                float* cp = &C[(long)(m + i) * N + nn];
                if (epi == 0) {
                    *cp = vv;
                } else if (epi == 1) {
                    vv += bias[nn];
                    *cp = vv > 20.f ? vv : log1pf(expf(vv));
                } else {
                    *cp += vv;
                }
            }
        }
    }
}

// ---------------- causal depthwise conv (k=4) + bias + silu -----------------
// u[b,l,d] = silu(sum_j xc[b,l-3+j,d]*w[d,j] + cb[d]);  xc = xz[:, :D_INNER]
__global__ __launch_bounds__(256) void conv_silu_kernel(const float* __restrict__ xz,
        const float* __restrict__ w, const float* __restrict__ cb,
        float* __restrict__ u) {
    int g = blockIdx.x * 256 + threadIdx.x;   // 0 .. 512*1536-1
    int d = g % D_INNER;
    int m = g / D_INNER;
    int l = m % SEQ;
    int b = m / SEQ;
    float acc = cb[d];
    #pragma unroll
    for (int j = 0; j < 4; ++j) {
        int ll = l - 3 + j;
        if (ll >= 0)
            acc += xz[(long)(b * SEQ + ll) * (2 * D_INNER) + d] * w[d * 4 + j];
    }
    u[(long)m * D_INNER + d] = siluf(acc);
}

// ---------------- selective scan + skip + z-gate ----------------------------
// one thread per (b, d, s); 16-lane groups share a (b,d)
__global__ __launch_bounds__(256) void scan_kernel(const float* __restrict__ dt,
        const float* __restrict__ u, const float* __restrict__ dbc,
        const float* __restrict__ xz, const float* __restrict__ A_log,
        const float* __restrict__ Dskip, const float* __restrict__ h0,
        float* __restrict__ y, float* __restrict__ outstate) {
    int g = blockIdx.x * 256 + threadIdx.x;    // 0 .. 49151
    int s = g & 15;
    int b = g / (D_INNER * D_STATE);
    int d = (g - b * D_INNER * D_STATE) >> 4;
    float A_s = -expf(A_log[d * D_STATE + s]);
    float hst = h0 ? h0[(long)(b * D_INNER + d) * D_STATE + s] : 0.0f;
    float Dv = Dskip[d];
    for (int l = 0; l < SEQ; ++l) {
        int m = b * SEQ + l;
        float dtv = dt[(long)m * D_INNER + d];
        float uv  = u[(long)m * D_INNER + d];
        float Bv  = dbc[m * DBC_COLS + DT_RANK + s];
        float Cv  = dbc[m * DBC_COLS + DT_RANK + D_STATE + s];
        float dA = expf(dtv * A_s);
        hst = dA * hst + dtv * Bv * uv;
        float p = hst * Cv;
        p += __shfl_xor(p, 1);
        p += __shfl_xor(p, 2);
        p += __shfl_xor(p, 4);
        p += __shfl_xor(p, 8);
        if (s == 0) {
            float zv = xz[(long)m * (2 * D_INNER) + D_INNER + d];
            y[(long)m * D_INNER + d] = (p + Dv * uv) * siluf(zv);
        }
    }
    if (outstate) outstate[(long)(b * D_INNER + d) * D_STATE + s] = hst;
}

// ---------------- h += time_embeds[timesteps[b], :] -------------------------
__global__ __launch_bounds__(256) void add_time_kernel(float* __restrict__ h,
        const float* __restrict__ te, const int* __restrict__ ts) {
    int g = blockIdx.x * 256 + threadIdx.x;   // 0 .. 512*768-1
    int m = g / D_MODEL;
    int k = g - m * D_MODEL;
    int b = m / SEQ;
    h[g] += te[(long)ts[b] * D_MODEL + k];
}

extern "C" void kernel_launch(void* const* d_in, const int* in_sizes, int n_in,
                              void* d_out, int out_size, void* d_ws, size_t ws_size,
                              hipStream_t stream) {
    const float* states     = (const float*)d_in[0];   // (3,2,1536,16)
    const int*   timesteps  = (const int*)d_in[1];     // (2,)
    const int*   input_ids  = (const int*)d_in[2];     // (2,256)
    const float* time_emb   = (const float*)d_in[3];   // (100,768)
    const float* embed      = (const float*)d_in[4];   // (50280,768)
    const float* norm_w     = (const float*)d_in[5];   // (24,768)
    const float* in_proj_w  = (const float*)d_in[6];   // (24,3072,768)
    const float* conv_w     = (const float*)d_in[7];   // (24,1536,4)
    const float* conv_b     = (const float*)d_in[8];   // (24,1536)
    const float* x_proj_w   = (const float*)d_in[9];   // (24,80,1536)
    const float* dt_proj_w  = (const float*)d_in[10];  // (24,1536,48)
    const float* dt_proj_b  = (const float*)d_in[11];  // (24,1536)
    const float* A_log      = (const float*)d_in[12];  // (24,1536,16)
    const float* D_skip     = (const float*)d_in[13];  // (24,1536)
    const float* out_proj_w = (const float*)d_in[14];  // (24,768,1536)
    float* out = (float*)d_out;                        // (3,2,1536,16)

    // workspace carve-up (fp32)
    float* h   = (float*)d_ws;                  // 512*768
    float* x   = h   + M_ROWS * D_MODEL;        // 512*768
    float* xz  = x   + M_ROWS * D_MODEL;        // 512*3072
    float* u   = xz  + M_ROWS * 2 * D_INNER;    // 512*1536
    float* dbc = u   + M_ROWS * D_INNER;        // 512*80
    float* dt  = dbc + M_ROWS * DBC_COLS;       // 512*1536
    float* y   = dt  + M_ROWS * D_INNER;        // 512*1536

    dim3 gblock(16, 16);

    gather_kernel<<<M_ROWS, 256, 0, stream>>>(input_ids, embed, h);

    for (int l = 0; l < NLAYERS; ++l) {
        const float* nw  = norm_w     + (size_t)l * D_MODEL;
        const float* iw  = in_proj_w  + (size_t)l * 2 * D_INNER * D_MODEL;
        const float* cw  = conv_w     + (size_t)l * D_INNER * 4;
        const float* cb  = conv_b     + (size_t)l * D_INNER;
        const float* xw  = x_proj_w   + (size_t)l * DBC_COLS * D_INNER;
        const float* dw  = dt_proj_w  + (size_t)l * D_INNER * DT_RANK;
        const float* db  = dt_proj_b  + (size_t)l * D_INNER;
        const float* al  = A_log      + (size_t)l * D_INNER * D_STATE;
        const float* dsk = D_skip     + (size_t)l * D_INNER;
        const float* ow  = out_proj_w + (size_t)l * D_MODEL * D_INNER;

        rmsnorm_kernel<<<M_ROWS, 256, 0, stream>>>(h, nw, x);

        // xz[512,3072] = x[512,768] @ in_w^T
        gemm_nt<<<dim3(2 * D_INNER / 64, M_ROWS / 64), gblock, 0, stream>>>(
            x, iw, xz, M_ROWS, 2 * D_INNER, D_MODEL, D_MODEL, nullptr, 0);

        conv_silu_kernel<<<M_ROWS * D_INNER / 256, 256, 0, stream>>>(xz, cw, cb, u);

        // dbc[512,80] = u[512,1536] @ x_w^T
        gemm_nt<<<dim3((DBC_COLS + 63) / 64, M_ROWS / 64), gblock, 0, stream>>>(
            u, xw, dbc, M_ROWS, DBC_COLS, D_INNER, D_INNER, nullptr, 0);

        // dt[512,1536] = softplus(dbc[:, :48] @ dt_w^T + dt_b)
        gemm_nt<<<dim3(D_INNER / 64, M_ROWS / 64), gblock, 0, stream>>>(
            dbc, dw, dt, M_ROWS, D_INNER, DT_RANK, DBC_COLS, db, 1);

        const float* h0  = (l >= 21) ? states + (size_t)(l - 21) * BATCH * D_INNER * D_STATE : nullptr;
        float* ostate    = (l >= 21) ? out + (size_t)(l - 21) * BATCH * D_INNER * D_STATE : nullptr;
        scan_kernel<<<BATCH * D_INNER * D_STATE / 256, 256, 0, stream>>>(
            dt, u, dbc, xz, al, dsk, h0, y, ostate);

        // h[512,768] += y[512,1536] @ out_w^T
        gemm_nt<<<dim3(D_MODEL / 64, M_ROWS / 64), gblock, 0, stream>>>(
            y, ow, h, M_ROWS, D_MODEL, D_INNER, D_INNER, nullptr, 2);

        if (l == 20) {
            add_time_kernel<<<M_ROWS * D_MODEL / 256, 256, 0, stream>>>(h, time_emb, timesteps);
        }
    }
}

// Round 3
// 5313.203 us; speedup vs baseline: 2.1462x; 2.1462x over previous
//
#include <hip/hip_runtime.h>
#include <math.h>

#define D_MODEL 768
#define D_INNER 1536
#define D_STATE 16
#define DT_RANK 48
#define NLAYERS 24
#define BATCH 2
#define SEQ 256
#define M_ROWS (BATCH*SEQ)   // 512
#define DBC_COLS (DT_RANK + 2*D_STATE)  // 80

__device__ __forceinline__ float siluf(float x) {
    return x / (1.0f + __expf(-x));
}

// ---------------- embedding gather: h[m,:] = embed[ids[m],:] ----------------
__global__ __launch_bounds__(256) void gather_kernel(const int* __restrict__ ids,
        const float* __restrict__ embed, float* __restrict__ h) {
    int m = blockIdx.x;
    long id = ids[m];
    const float* src = embed + id * D_MODEL;
    float* dst = h + m * D_MODEL;
    for (int k = threadIdx.x; k < D_MODEL; k += 256) dst[k] = src[k];
}

// ---------------- RMS norm ---------------------------------------------------
__global__ __launch_bounds__(256) void rmsnorm_kernel(const float* __restrict__ h,
        const float* __restrict__ w, float* __restrict__ x) {
    int m = blockIdx.x;
    const float* row = h + m * D_MODEL;
    float v[3];
    float ss = 0.f;
    #pragma unroll
    for (int i = 0; i < 3; ++i) {
        v[i] = row[threadIdx.x + i * 256];
        ss += v[i] * v[i];
    }
    #pragma unroll
    for (int off = 32; off > 0; off >>= 1) ss += __shfl_down(ss, off);
    __shared__ float wsum[4];
    int lane = threadIdx.x & 63, wid = threadIdx.x >> 6;
    if (lane == 0) wsum[wid] = ss;
    __syncthreads();
    float tot = wsum[0] + wsum[1] + wsum[2] + wsum[3];
    float inv = rsqrtf(tot / (float)D_MODEL + 1e-5f);
    float* xrow = x + m * D_MODEL;
    #pragma unroll
    for (int i = 0; i < 3; ++i) {
        int k = threadIdx.x + i * 256;
        xrow[k] = v[i] * inv * w[k];
    }
}

// ---------------- NT GEMM: C[M,N] (op)= A[M,K(lda)] * B[N,K]^T --------------
// epi: 0 = store, 1 = softplus(acc + bias[n]) store, 2 = accumulate (+=)
#define KT 16
__global__ __launch_bounds__(256) void gemm_nt(const float* __restrict__ A,
        const float* __restrict__ B, float* __restrict__ C,
        int M, int N, int K, int lda,
        const float* __restrict__ bias, int epi) {
    __shared__ __align__(16) float As[KT][68];
    __shared__ __align__(16) float Bs[KT][68];
    int tx = threadIdx.x, ty = threadIdx.y;
    int tid = ty * 16 + tx;
    int m0 = blockIdx.y * 64, n0 = blockIdx.x * 64;
    int lr = tid >> 2;
    int lc = (tid & 3) * 4;
    const float* Aptr = A + (long)(m0 + lr) * lda + lc;
    const float* Bptr = B + (long)(n0 + lr) * K + lc;
    bool bvalid = (n0 + lr) < N;
    float acc[4][4] = {};
    for (int k0 = 0; k0 < K; k0 += KT) {
        float4 av = *(const float4*)(Aptr + k0);
        float4 bv = bvalid ? *(const float4*)(Bptr + k0) : make_float4(0.f, 0.f, 0.f, 0.f);
        As[lc + 0][lr] = av.x; As[lc + 1][lr] = av.y;
        As[lc + 2][lr] = av.z; As[lc + 3][lr] = av.w;
        Bs[lc + 0][lr] = bv.x; Bs[lc + 1][lr] = bv.y;
        Bs[lc + 2][lr] = bv.z; Bs[lc + 3][lr] = bv.w;
        __syncthreads();
        #pragma unroll
        for (int kk = 0; kk < KT; ++kk) {
            float4 a = *(const float4*)&As[kk][ty * 4];
            float4 b = *(const float4*)&Bs[kk][tx * 4];
            acc[0][0] += a.x * b.x; acc[0][1] += a.x * b.y; acc[0][2] += a.x * b.z; acc[0][3] += a.x * b.w;
            acc[1][0] += a.y * b.x; acc[1][1] += a.y * b.y; acc[1][2] += a.y * b.z; acc[1][3] += a.y * b.w;
            acc[2][0] += a.z * b.x; acc[2][1] += a.z * b.y; acc[2][2] += a.z * b.z; acc[2][3] += a.z * b.w;
            acc[3][0] += a.w * b.x; acc[3][1] += a.w * b.y; acc[3][2] += a.w * b.z; acc[3][3] += a.w * b.w;
        }
        __syncthreads();
    }
    int m = m0 + ty * 4, n = n0 + tx * 4;
    #pragma unroll
    for (int i = 0; i < 4; ++i) {
        #pragma unroll
        for (int j = 0; j < 4; ++j) {
            int nn = n + j;
            if (nn < N) {
                float vv = acc[i][j];
                float* cp = &C[(long)(m + i) * N + nn];
                if (epi == 0) {
                    *cp = vv;
                } else if (epi == 1) {
                    vv += bias[nn];
                    *cp = vv > 20.f ? vv : log1pf(expf(vv));
                } else {
                    *cp += vv;
                }
            }
        }
    }
}

// ---------------- split-K NT GEMM: P[z][M][N] = A * B^T over K-chunk z ------
__global__ __launch_bounds__(256) void gemm_nt_splitk(const float* __restrict__ A,
        const float* __restrict__ B, float* __restrict__ P,
        int M, int N, int K, int lda, int kchunk) {
    __shared__ __align__(16) float As[KT][68];
    __shared__ __align__(16) float Bs[KT][68];
    int tx = threadIdx.x, ty = threadIdx.y;
    int tid = ty * 16 + tx;
    int m0 = blockIdx.y * 64, n0 = blockIdx.x * 64;
    int kbeg = blockIdx.z * kchunk;
    int lr = tid >> 2;
    int lc = (tid & 3) * 4;
    const float* Aptr = A + (long)(m0 + lr) * lda + kbeg + lc;
    const float* Bptr = B + (long)(n0 + lr) * K + kbeg + lc;
    bool bvalid = (n0 + lr) < N;
    float acc[4][4] = {};
    for (int k0 = 0; k0 < kchunk; k0 += KT) {
        float4 av = *(const float4*)(Aptr + k0);
        float4 bv = bvalid ? *(const float4*)(Bptr + k0) : make_float4(0.f, 0.f, 0.f, 0.f);
        As[lc + 0][lr] = av.x; As[lc + 1][lr] = av.y;
        As[lc + 2][lr] = av.z; As[lc + 3][lr] = av.w;
        Bs[lc + 0][lr] = bv.x; Bs[lc + 1][lr] = bv.y;
        Bs[lc + 2][lr] = bv.z; Bs[lc + 3][lr] = bv.w;
        __syncthreads();
        #pragma unroll
        for (int kk = 0; kk < KT; ++kk) {
            float4 a = *(const float4*)&As[kk][ty * 4];
            float4 b = *(const float4*)&Bs[kk][tx * 4];
            acc[0][0] += a.x * b.x; acc[0][1] += a.x * b.y; acc[0][2] += a.x * b.z; acc[0][3] += a.x * b.w;
            acc[1][0] += a.y * b.x; acc[1][1] += a.y * b.y; acc[1][2] += a.y * b.z; acc[1][3] += a.y * b.w;
            acc[2][0] += a.z * b.x; acc[2][1] += a.z * b.y; acc[2][2] += a.z * b.z; acc[2][3] += a.z * b.w;
            acc[3][0] += a.w * b.x; acc[3][1] += a.w * b.y; acc[3][2] += a.w * b.z; acc[3][3] += a.w * b.w;
        }
        __syncthreads();
    }
    float* Pz = P + (size_t)blockIdx.z * M * N;
    int m = m0 + ty * 4, n = n0 + tx * 4;
    #pragma unroll
    for (int i = 0; i < 4; ++i)
        #pragma unroll
        for (int j = 0; j < 4; ++j) {
            int nn = n + j;
            if (nn < N) Pz[(long)(m + i) * N + nn] = acc[i][j];
        }
}

// ---------------- reduce 4 split-K partials ---------------------------------
__global__ __launch_bounds__(256) void reduce_splitk(const float* __restrict__ P,
        float* __restrict__ C, int MN, int accum) {
    int i = blockIdx.x * 256 + threadIdx.x;
    if (i < MN) {
        float v = P[i] + P[MN + i] + P[2 * MN + i] + P[3 * MN + i];
        if (accum) C[i] += v; else C[i] = v;
    }
}

// ---------------- causal depthwise conv (k=4) + bias + silu -----------------
__global__ __launch_bounds__(256) void conv_silu_kernel(const float* __restrict__ xz,
        const float* __restrict__ w, const float* __restrict__ cb,
        float* __restrict__ u) {
    int g = blockIdx.x * 256 + threadIdx.x;
    int d = g % D_INNER;
    int m = g / D_INNER;
    int l = m % SEQ;
    int b = m / SEQ;
    float acc = cb[d];
    #pragma unroll
    for (int j = 0; j < 4; ++j) {
        int ll = l - 3 + j;
        if (ll >= 0)
            acc += xz[(long)(b * SEQ + ll) * (2 * D_INNER) + d] * w[d * 4 + j];
    }
    u[(long)m * D_INNER + d] = siluf(acc);
}

// ---------------- selective scan + skip + z-gate (LDS-tiled) ----------------
// 192 blocks x 256 threads; block owns 16 (b,d) pairs; lane s in [0,16)
#define SCAN_TILE 64
__global__ __launch_bounds__(256) void scan_kernel(const float* __restrict__ dt,
        const float* __restrict__ u, const float* __restrict__ dbc,
        const float* __restrict__ xz, const float* __restrict__ A_log,
        const float* __restrict__ Dskip, const float* __restrict__ h0,
        float* __restrict__ y, float* __restrict__ outstate) {
    __shared__ float sdt[SCAN_TILE][16];
    __shared__ float su [SCAN_TILE][16];
    __shared__ float sz [SCAN_TILE][16];
    __shared__ float sBC[SCAN_TILE][32];
    __shared__ float sy [SCAN_TILE][16];
    int t = threadIdx.x;
    int s = t & 15;
    int pair = t >> 4;                         // 0..15
    int gp = blockIdx.x * 16 + pair;
    int b = gp / D_INNER;                      // uniform per block (96 blocks per batch)
    int d = gp % D_INNER;
    int d0 = (blockIdx.x * 16) % D_INNER;      // block's base d
    float A_s = -__expf(A_log[d * D_STATE + s]);
    float hst = h0 ? h0[(size_t)(b * D_INNER + d) * D_STATE + s] : 0.0f;
    float Dv = Dskip[d];
    for (int l0 = 0; l0 < SEQ; l0 += SCAN_TILE) {
        // ---- stage tile (coalesced) ----
        #pragma unroll
        for (int k = 0; k < 4; ++k) {
            int idx = t + k * 256;
            int l = idx >> 4, j = idx & 15;
            size_t m = (size_t)(b * SEQ + l0 + l);
            sdt[l][j] = dt[m * D_INNER + d0 + j];
            su [l][j] = u [m * D_INNER + d0 + j];
            float zv  = xz[m * (2 * D_INNER) + D_INNER + d0 + j];
            sz [l][j] = siluf(zv);
        }
        #pragma unroll
        for (int k = 0; k < 8; ++k) {
            int idx = t + k * 256;
            int l = idx >> 5, c = idx & 31;
            size_t m = (size_t)(b * SEQ + l0 + l);
            sBC[l][c] = dbc[m * DBC_COLS + DT_RANK + c];
        }
        __syncthreads();
        // ---- serial recurrence over the tile ----
        #pragma unroll 4
        for (int l = 0; l < SCAN_TILE; ++l) {
            float dtv = sdt[l][pair];
            float uv  = su [l][pair];
            float Bv  = sBC[l][s];
            float Cv  = sBC[l][16 + s];
            float dA = __expf(dtv * A_s);
            hst = dA * hst + dtv * Bv * uv;
            float p = hst * Cv;
            p += __shfl_xor(p, 1);
            p += __shfl_xor(p, 2);
            p += __shfl_xor(p, 4);
            p += __shfl_xor(p, 8);
            if (s == 0) sy[l][pair] = (p + Dv * uv) * sz[l][pair];
        }
        __syncthreads();
        // ---- flush y (coalesced) ----
        #pragma unroll
        for (int k = 0; k < 4; ++k) {
            int idx = t + k * 256;
            int l = idx >> 4, j = idx & 15;
            size_t m = (size_t)(b * SEQ + l0 + l);
            y[m * D_INNER + d0 + j] = sy[l][j];
        }
    }
    if (outstate) outstate[(size_t)(b * D_INNER + d) * D_STATE + s] = hst;
}

// ---------------- h += time_embeds[timesteps[b], :] -------------------------
__global__ __launch_bounds__(256) void add_time_kernel(float* __restrict__ h,
        const float* __restrict__ te, const int* __restrict__ ts) {
    int g = blockIdx.x * 256 + threadIdx.x;
    int m = g / D_MODEL;
    int k = g - m * D_MODEL;
    int b = m / SEQ;
    h[g] += te[(long)ts[b] * D_MODEL + k];
}

extern "C" void kernel_launch(void* const* d_in, const int* in_sizes, int n_in,
                              void* d_out, int out_size, void* d_ws, size_t ws_size,
                              hipStream_t stream) {
    const float* states     = (const float*)d_in[0];
    const int*   timesteps  = (const int*)d_in[1];
    const int*   input_ids  = (const int*)d_in[2];
    const float* time_emb   = (const float*)d_in[3];
    const float* embed      = (const float*)d_in[4];
    const float* norm_w     = (const float*)d_in[5];
    const float* in_proj_w  = (const float*)d_in[6];
    const float* conv_w     = (const float*)d_in[7];
    const float* conv_b     = (const float*)d_in[8];
    const float* x_proj_w   = (const float*)d_in[9];
    const float* dt_proj_w  = (const float*)d_in[10];
    const float* dt_proj_b  = (const float*)d_in[11];
    const float* A_log      = (const float*)d_in[12];
    const float* D_skip     = (const float*)d_in[13];
    const float* out_proj_w = (const float*)d_in[14];
    float* out = (float*)d_out;

    // workspace carve-up (fp32)
    float* h   = (float*)d_ws;                  // 393216
    float* x   = h   + M_ROWS * D_MODEL;        // 393216
    float* xz  = x   + M_ROWS * D_MODEL;        // 1572864
    float* u   = xz  + M_ROWS * 2 * D_INNER;    // 786432
    float* dbc = u   + M_ROWS * D_INNER;        // 40960
    float* dt  = dbc + M_ROWS * DBC_COLS;       // 786432
    float* y   = dt  + M_ROWS * D_INNER;        // 786432
    // aliased split-K partial buffers (lifetimes verified):
    float* px  = x;   // 4*512*80 = 163840 <= 393216; x dead after in_proj GEMM
    float* po  = u;   // 4*512*768 = 1572864 <= u+dbc+dt span (1613824); all dead after scan

    dim3 gblock(16, 16);

    gather_kernel<<<M_ROWS, 256, 0, stream>>>(input_ids, embed, h);

    for (int l = 0; l < NLAYERS; ++l) {
        const float* nw  = norm_w     + (size_t)l * D_MODEL;
        const float* iw  = in_proj_w  + (size_t)l * 2 * D_INNER * D_MODEL;
        const float* cw  = conv_w     + (size_t)l * D_INNER * 4;
        const float* cb  = conv_b     + (size_t)l * D_INNER;
        const float* xw  = x_proj_w   + (size_t)l * DBC_COLS * D_INNER;
        const float* dw  = dt_proj_w  + (size_t)l * D_INNER * DT_RANK;
        const float* db  = dt_proj_b  + (size_t)l * D_INNER;
        const float* al  = A_log      + (size_t)l * D_INNER * D_STATE;
        const float* dsk = D_skip     + (size_t)l * D_INNER;
        const float* ow  = out_proj_w + (size_t)l * D_MODEL * D_INNER;

        rmsnorm_kernel<<<M_ROWS, 256, 0, stream>>>(h, nw, x);

        // xz[512,3072] = x[512,768] @ in_w^T
        gemm_nt<<<dim3(2 * D_INNER / 64, M_ROWS / 64), gblock, 0, stream>>>(
            x, iw, xz, M_ROWS, 2 * D_INNER, D_MODEL, D_MODEL, nullptr, 0);

        conv_silu_kernel<<<M_ROWS * D_INNER / 256, 256, 0, stream>>>(xz, cw, cb, u);

        // dbc[512,80] = u[512,1536] @ x_w^T   (split-K x4)
        gemm_nt_splitk<<<dim3(2, M_ROWS / 64, 4), gblock, 0, stream>>>(
            u, xw, px, M_ROWS, DBC_COLS, D_INNER, D_INNER, D_INNER / 4);
        reduce_splitk<<<(M_ROWS * DBC_COLS + 255) / 256, 256, 0, stream>>>(
            px, dbc, M_ROWS * DBC_COLS, 0);

        // dt[512,1536] = softplus(dbc[:, :48] @ dt_w^T + dt_b)
        gemm_nt<<<dim3(D_INNER / 64, M_ROWS / 64), gblock, 0, stream>>>(
            dbc, dw, dt, M_ROWS, D_INNER, DT_RANK, DBC_COLS, db, 1);

        const float* h0  = (l >= 21) ? states + (size_t)(l - 21) * BATCH * D_INNER * D_STATE : nullptr;
        float* ostate    = (l >= 21) ? out + (size_t)(l - 21) * BATCH * D_INNER * D_STATE : nullptr;
        scan_kernel<<<BATCH * D_INNER / 16, 256, 0, stream>>>(
            dt, u, dbc, xz, al, dsk, h0, y, ostate);

        // h[512,768] += y[512,1536] @ out_w^T   (split-K x4)
        gemm_nt_splitk<<<dim3(D_MODEL / 64, M_ROWS / 64, 4), gblock, 0, stream>>>(
            y, ow, po, M_ROWS, D_MODEL, D_INNER, D_INNER, D_INNER / 4);
        reduce_splitk<<<(M_ROWS * D_MODEL + 255) / 256, 256, 0, stream>>>(
            po, h, M_ROWS * D_MODEL, 1);

        if (l == 20) {
            add_time_kernel<<<M_ROWS * D_MODEL / 256, 256, 0, stream>>>(h, time_emb, timesteps);
        }
    }
}